// Round 2
// baseline (281.887 us; speedup 1.0000x reference)
//
#include <hip/hip_runtime.h>

#define W 512
#define H 512
#define NSLICES 48          // 16 batch * 3 channels
#define TX 32
#define TY 32
#define HALO 5
#define KS 11
#define ITY (TY + 2*HALO)   // 42 hconv rows
#define HBS 36              // hb row stride in floats
#define C1_SSIM 0.0001f     // 0.01^2
#define C2_SSIM 0.0009f     // 0.03^2
#define NTOTAL 12582912.0f  // 16*3*512*512

__device__ inline float ssim_px(float ux, float uy, float uxx, float uyy, float uxy) {
    const float uxuy = ux * uy;
    const float a = 2.f * uxuy + C1_SSIM;
    const float b = 2.f * (uxy - uxuy) + C2_SSIM;
    const float c = ux * ux + uy * uy + C1_SSIM;
    const float d = (uxx - ux * ux) + (uyy - uy * uy) + C2_SSIM;
    return (a * b) / (c * d);
}

// LDS: only the 5-channel horizontal-conv intermediate. 5*42*36*4 = 30240 B
// -> 5 blocks/CU (vs 42 KB / 3 blocks in R1).
__global__ __launch_bounds__(256, 5)
void ssim_main(const float* __restrict__ simg, const float* __restrict__ timg,
               float* __restrict__ accum) {
    __shared__ float hb[5][ITY][HBS];
    __shared__ float red[4];

    const int tid = threadIdx.x;
    const int bz = blockIdx.z;
    const float* sp = simg + (size_t)bz * (W * H);
    const float* tp = timg + (size_t)bz * (W * H);
    const int x0 = blockIdx.x * TX;
    const int y0 = blockIdx.y * TY - HALO;

    // Normalized 1-D Gaussian weights, recomputed per thread (deterministic,
    // matches reference's float32 normalization to ~1e-7; threshold is 2e-2).
    float g[KS];
    {
        float ssum = 0.f;
        #pragma unroll
        for (int i = 0; i < KS; ++i) {
            const float ax = (float)i - 5.0f;
            g[i] = expf(-ax * ax * (1.0f / 4.5f));
            ssum += g[i];
        }
        const float inv = 1.0f / ssum;
        #pragma unroll
        for (int i = 0; i < KS; ++i) g[i] *= inv;
    }

    // ---- Horizontal pass straight from global into registers, write hb ----
    // 42 rows x 8 quads-of-4 = 336 items; each loads a 20-float window
    // (5x float4, 16B-aligned) per image and emits 4 outputs x 5 channels.
    for (int it = tid; it < ITY * 8; it += 256) {
        const int yy = it >> 3;
        const int q  = it & 7;
        const int ox = q * 4;
        const int gy = y0 + yy;
        float hs[4]  = {0, 0, 0, 0};
        float ht[4]  = {0, 0, 0, 0};
        float hss[4] = {0, 0, 0, 0};
        float htt[4] = {0, 0, 0, 0};
        float hst[4] = {0, 0, 0, 0};
        if ((unsigned)gy < (unsigned)H) {
            const float* rs = sp + (size_t)gy * W;
            const float* rt = tp + (size_t)gy * W;
            const int xb = x0 + ox - 8;       // window covers [xb, xb+19]
            float vs[20], vt[20];
            #pragma unroll
            for (int i = 0; i < 5; ++i) {
                const int xx = xb + 4 * i;
                float4 a, b;
                if (xx >= 0 && xx + 3 < W) {
                    a = *(const float4*)(rs + xx);
                    b = *(const float4*)(rt + xx);
                } else {
                    a.x = ((unsigned)(xx + 0) < (unsigned)W) ? rs[xx + 0] : 0.f;
                    a.y = ((unsigned)(xx + 1) < (unsigned)W) ? rs[xx + 1] : 0.f;
                    a.z = ((unsigned)(xx + 2) < (unsigned)W) ? rs[xx + 2] : 0.f;
                    a.w = ((unsigned)(xx + 3) < (unsigned)W) ? rs[xx + 3] : 0.f;
                    b.x = ((unsigned)(xx + 0) < (unsigned)W) ? rt[xx + 0] : 0.f;
                    b.y = ((unsigned)(xx + 1) < (unsigned)W) ? rt[xx + 1] : 0.f;
                    b.z = ((unsigned)(xx + 2) < (unsigned)W) ? rt[xx + 2] : 0.f;
                    b.w = ((unsigned)(xx + 3) < (unsigned)W) ? rt[xx + 3] : 0.f;
                }
                vs[4*i+0] = a.x; vs[4*i+1] = a.y; vs[4*i+2] = a.z; vs[4*i+3] = a.w;
                vt[4*i+0] = b.x; vt[4*i+1] = b.y; vt[4*i+2] = b.z; vt[4*i+3] = b.w;
            }
            // outputs m (=ox+m) need inputs [4q-5+m .. 4q+5+m] -> vs[3+m+k]
            #pragma unroll
            for (int k = 0; k < KS; ++k) {
                const float gk = g[k];
                #pragma unroll
                for (int m = 0; m < 4; ++m) {
                    const float sv = vs[3 + m + k];
                    const float tv = vt[3 + m + k];
                    const float gs = gk * sv;
                    const float gt = gk * tv;
                    hs[m]  += gs;
                    ht[m]  += gt;
                    hss[m] = fmaf(gs, sv, hss[m]);
                    htt[m] = fmaf(gt, tv, htt[m]);
                    hst[m] = fmaf(gs, tv, hst[m]);
                }
            }
        }
        *(float4*)&hb[0][yy][ox] = make_float4(hs[0],  hs[1],  hs[2],  hs[3]);
        *(float4*)&hb[1][yy][ox] = make_float4(ht[0],  ht[1],  ht[2],  ht[3]);
        *(float4*)&hb[2][yy][ox] = make_float4(hss[0], hss[1], hss[2], hss[3]);
        *(float4*)&hb[3][yy][ox] = make_float4(htt[0], htt[1], htt[2], htt[3]);
        *(float4*)&hb[4][yy][ox] = make_float4(hst[0], hst[1], hst[2], hst[3]);
    }
    __syncthreads();

    // ---- Vertical pass: column per thread, 4 stacked y-outputs ----
    // Lane = x -> 32 lanes span 32 banks (scalar b32, conflict-free; the
    // cross-half-wave 2-way alias is free). 14 rows x 5 ch reads, 220 FMAs.
    const int x  = tid & 31;
    const int yb = (tid >> 5) * 4;
    float aux[4]  = {0, 0, 0, 0};
    float auy[4]  = {0, 0, 0, 0};
    float auxx[4] = {0, 0, 0, 0};
    float auyy[4] = {0, 0, 0, 0};
    float auxy[4] = {0, 0, 0, 0};
    #pragma unroll
    for (int k = 0; k < TY / 8 + KS - 1 + 3; ++k) { /* k = 0..13 */
        const float vx  = hb[0][yb + k][x];
        const float vy  = hb[1][yb + k][x];
        const float vxx = hb[2][yb + k][x];
        const float vyy = hb[3][yb + k][x];
        const float vxy = hb[4][yb + k][x];
        #pragma unroll
        for (int o = 0; o < 4; ++o) {
            const int j = k - o;
            if (j >= 0 && j < KS) {
                const float gj = g[j];
                aux[o]  = fmaf(gj, vx,  aux[o]);
                auy[o]  = fmaf(gj, vy,  auy[o]);
                auxx[o] = fmaf(gj, vxx, auxx[o]);
                auyy[o] = fmaf(gj, vyy, auyy[o]);
                auxy[o] = fmaf(gj, vxy, auxy[o]);
            }
        }
    }
    float sum = ssim_px(aux[0], auy[0], auxx[0], auyy[0], auxy[0])
              + ssim_px(aux[1], auy[1], auxx[1], auyy[1], auxy[1])
              + ssim_px(aux[2], auy[2], auxx[2], auyy[2], auxy[2])
              + ssim_px(aux[3], auy[3], auxx[3], auyy[3], auxy[3]);

    // ---- Block reduction ----
    #pragma unroll
    for (int off = 32; off > 0; off >>= 1)
        sum += __shfl_down(sum, off, 64);
    if ((tid & 63) == 0) red[tid >> 6] = sum;
    __syncthreads();
    if (tid == 0) {
        atomicAdd(accum, red[0] + red[1] + red[2] + red[3]);
    }
}

__global__ void ssim_final(const float* __restrict__ accum, float* __restrict__ out) {
    out[0] = 1.f - accum[0] * (1.f / NTOTAL);
}

extern "C" void kernel_launch(void* const* d_in, const int* in_sizes, int n_in,
                              void* d_out, int out_size, void* d_ws, size_t ws_size,
                              hipStream_t stream) {
    const float* s = (const float*)d_in[0];
    const float* t = (const float*)d_in[1];
    float* out   = (float*)d_out;
    float* accum = (float*)d_ws;

    hipMemsetAsync(accum, 0, sizeof(float), stream);
    dim3 grid(W / TX, H / TY, NSLICES);
    ssim_main<<<grid, 256, 0, stream>>>(s, t, accum);
    ssim_final<<<1, 1, 0, stream>>>(accum, out);
}

// Round 3
// 184.110 us; speedup vs baseline: 1.5311x; 1.5311x over previous
//
#include <hip/hip_runtime.h>

#define W 512
#define H 512
#define NSLICES 48          // 16 batch * 3 channels
#define TX 32
#define TY 32
#define HALO 5
#define KS 11
#define ITY (TY + 2*HALO)   // 42 hconv rows
#define HBS 32              // hb row stride (b128-aligned writes, conflict-free scalar col reads)
#define C1_SSIM 0.0001f
#define C2_SSIM 0.0009f
#define NTOTAL 12582912.0f  // 16*3*512*512

// Normalized separable Gaussian (ksize=11, sigma=1.5), f32, matches reference
// row-sums to ~1e-7 (threshold is 1.98e-2).
__device__ __constant__ const float GW[KS] = {
    1.02838e-3f, 7.59876e-3f, 3.600076e-2f, 1.0936069e-1f, 2.1300554e-1f,
    2.6601172e-1f,
    2.1300554e-1f, 1.0936069e-1f, 3.600076e-2f, 7.59876e-3f, 1.02838e-3f
};

__device__ inline float ssim_px(float ux, float uy, float uxx, float uyy, float uxy) {
    const float uxuy = ux * uy;
    const float a = 2.f * uxuy + C1_SSIM;
    const float b = 2.f * (uxy - uxuy) + C2_SSIM;
    const float c = ux * ux + uy * uy + C1_SSIM;
    const float d = (uxx - ux * ux) + (uyy - uy * uy) + C2_SSIM;
    return (a * b) * __builtin_amdgcn_rcpf(c * d);
}

// LDS: 5*42*32*4 = 26880 B + red -> 27136 alloc -> 6 blocks/CU (24 waves).
__global__ __launch_bounds__(256, 6)
void ssim_main(const float* __restrict__ simg, const float* __restrict__ timg,
               float* __restrict__ accum) {
    __shared__ float hb[5][ITY][HBS];
    __shared__ float red[4];

    const int tid = threadIdx.x;

    // XCD-aware remap (assumes XCD = linear_id % 8; perf-only, correctness-safe):
    // each XCD owns 6 contiguous slices, row-major tiles within a slice.
    const int lin = blockIdx.x;
    const int t   = ((lin & 7) * (12288 / 8)) + (lin >> 3);
    const int z   = t >> 8;          // slice (batch*channel)
    const int rem = t & 255;
    const int ty  = rem >> 4;
    const int tx  = rem & 15;

    const float* sp = simg + (size_t)z * (W * H);
    const float* tp = timg + (size_t)z * (W * H);
    const int x0 = tx * TX;
    const int y0 = ty * TY - HALO;

    // ---- Horizontal pass: 42 rows x 8 quads = 336 items over 256 threads ----
    for (int it = tid; it < ITY * 8; it += 256) {
        const int yy = it >> 3;
        const int q  = it & 7;
        const int ox = q * 4;
        const int gy = y0 + yy;
        float hs[4]  = {0, 0, 0, 0};
        float ht[4]  = {0, 0, 0, 0};
        float hss[4] = {0, 0, 0, 0};
        float htt[4] = {0, 0, 0, 0};
        float hst[4] = {0, 0, 0, 0};
        if ((unsigned)gy < (unsigned)H) {
            const float* rs = sp + (size_t)gy * W;
            const float* rt = tp + (size_t)gy * W;
            const int xb = x0 + ox - 8;      // window元素 u -> global col xb+u; u=3..16 live
            float cs[20], ct[20];
            if (xb >= 0 && xb <= W - 20) {   // interior fast path: 5+5 aligned float4
                #pragma unroll
                for (int i = 0; i < 5; ++i) {
                    const float4 a = *(const float4*)(rs + xb + 4 * i);
                    const float4 b = *(const float4*)(rt + xb + 4 * i);
                    cs[4*i+0] = a.x; cs[4*i+1] = a.y; cs[4*i+2] = a.z; cs[4*i+3] = a.w;
                    ct[4*i+0] = b.x; ct[4*i+1] = b.y; ct[4*i+2] = b.z; ct[4*i+3] = b.w;
                }
            } else {                          // edge: guard only the 14 live elements
                #pragma unroll
                for (int u = 3; u <= 16; ++u) {
                    const int xx = xb + u;
                    const bool ok = (unsigned)xx < (unsigned)W;
                    cs[u] = ok ? rs[xx] : 0.f;
                    ct[u] = ok ? rt[xx] : 0.f;
                }
            }
            // out col (ox+m) tap k uses element u = m + k + 3
            #pragma unroll
            for (int u = 3; u <= 16; ++u) {
                const float sv = cs[u], tv = ct[u];
                const float ssv = sv * sv;
                const float ttv = tv * tv;
                const float stv = sv * tv;
                #pragma unroll
                for (int m = 0; m < 4; ++m) {
                    const int k = u - 3 - m;
                    if (k >= 0 && k < KS) {
                        const float gk = GW[k];
                        hs[m]  = fmaf(gk, sv,  hs[m]);
                        ht[m]  = fmaf(gk, tv,  ht[m]);
                        hss[m] = fmaf(gk, ssv, hss[m]);
                        htt[m] = fmaf(gk, ttv, htt[m]);
                        hst[m] = fmaf(gk, stv, hst[m]);
                    }
                }
            }
        }
        *(float4*)&hb[0][yy][ox] = make_float4(hs[0],  hs[1],  hs[2],  hs[3]);
        *(float4*)&hb[1][yy][ox] = make_float4(ht[0],  ht[1],  ht[2],  ht[3]);
        *(float4*)&hb[2][yy][ox] = make_float4(hss[0], hss[1], hss[2], hss[3]);
        *(float4*)&hb[3][yy][ox] = make_float4(htt[0], htt[1], htt[2], htt[3]);
        *(float4*)&hb[4][yy][ox] = make_float4(hst[0], hst[1], hst[2], hst[3]);
    }
    __syncthreads();

    // ---- Vertical pass: lane = x (conflict-free), 4 stacked y-outputs ----
    const int x  = tid & 31;
    const int yb = (tid >> 5) * 4;
    float aux[4]  = {0, 0, 0, 0};
    float auy[4]  = {0, 0, 0, 0};
    float auxx[4] = {0, 0, 0, 0};
    float auyy[4] = {0, 0, 0, 0};
    float auxy[4] = {0, 0, 0, 0};
    #pragma unroll
    for (int k = 0; k < 14; ++k) {
        const float vx  = hb[0][yb + k][x];
        const float vy  = hb[1][yb + k][x];
        const float vxx = hb[2][yb + k][x];
        const float vyy = hb[3][yb + k][x];
        const float vxy = hb[4][yb + k][x];
        #pragma unroll
        for (int o = 0; o < 4; ++o) {
            const int j = k - o;
            if (j >= 0 && j < KS) {
                const float gj = GW[j];
                aux[o]  = fmaf(gj, vx,  aux[o]);
                auy[o]  = fmaf(gj, vy,  auy[o]);
                auxx[o] = fmaf(gj, vxx, auxx[o]);
                auyy[o] = fmaf(gj, vyy, auyy[o]);
                auxy[o] = fmaf(gj, vxy, auxy[o]);
            }
        }
    }
    float sum = ssim_px(aux[0], auy[0], auxx[0], auyy[0], auxy[0])
              + ssim_px(aux[1], auy[1], auxx[1], auyy[1], auxy[1])
              + ssim_px(aux[2], auy[2], auxx[2], auyy[2], auxy[2])
              + ssim_px(aux[3], auy[3], auxx[3], auyy[3], auxy[3]);

    // ---- Block reduction, one atomic per block into per-slice line ----
    #pragma unroll
    for (int off = 32; off > 0; off >>= 1)
        sum += __shfl_down(sum, off, 64);
    if ((tid & 63) == 0) red[tid >> 6] = sum;
    __syncthreads();
    if (tid == 0) {
        atomicAdd(&accum[z * 16], red[0] + red[1] + red[2] + red[3]);
    }
}

__global__ void ssim_final(const float* __restrict__ accum, float* __restrict__ out) {
    float s = 0.f;
    #pragma unroll
    for (int i = 0; i < NSLICES; ++i) s += accum[i * 16];
    out[0] = 1.f - s * (1.f / NTOTAL);
}

extern "C" void kernel_launch(void* const* d_in, const int* in_sizes, int n_in,
                              void* d_out, int out_size, void* d_ws, size_t ws_size,
                              hipStream_t stream) {
    const float* s = (const float*)d_in[0];
    const float* t = (const float*)d_in[1];
    float* out   = (float*)d_out;
    float* accum = (float*)d_ws;

    hipMemsetAsync(accum, 0, NSLICES * 16 * sizeof(float), stream);
    ssim_main<<<dim3(12288), 256, 0, stream>>>(s, t, accum);
    ssim_final<<<1, 1, 0, stream>>>(accum, out);
}

// Round 4
// 167.387 us; speedup vs baseline: 1.6840x; 1.0999x over previous
//
#include <hip/hip_runtime.h>

#define W 512
#define H 512
#define NSLICES 48          // 16 batch * 3 channels
#define TX 32
#define TY 64
#define HALO 5
#define KS 11
#define ITY (TY + 2*HALO)   // 74 hconv rows
#define HBS 32              // hb row stride
#define NBLK 6144           // 16 x-tiles * 8 y-tiles * 48 slices
#define C1_SSIM 0.0001f
#define C2_SSIM 0.0009f
#define NTOTAL 12582912.0f  // 16*3*512*512

// Normalized separable Gaussian (ksize=11, sigma=1.5), f32; matches the
// reference's normalized row-sums to ~1e-7 (threshold 1.98e-2).
__device__ __constant__ const float GW[KS] = {
    1.02838e-3f, 7.59876e-3f, 3.600076e-2f, 1.0936069e-1f, 2.1300554e-1f,
    2.6601172e-1f,
    2.1300554e-1f, 1.0936069e-1f, 3.600076e-2f, 7.59876e-3f, 1.02838e-3f
};

__device__ inline float ssim_px(float ux, float uy, float uxx, float uyy, float uxy) {
    const float uxuy = ux * uy;
    const float a = 2.f * uxuy + C1_SSIM;
    const float b = 2.f * (uxy - uxuy) + C2_SSIM;
    const float c = ux * ux + uy * uy + C1_SSIM;
    const float d = (uxx - ux * ux) + (uyy - uy * uy) + C2_SSIM;
    return (a * b) * __builtin_amdgcn_rcpf(c * d);
}

// LDS: 5*74*32*4 = 47360 B -> 3 blocks/CU (12 waves). Tall tile trades
// occupancy for -12% hconv halo math and -36% vconv LDS reads per pixel.
__global__ __launch_bounds__(256, 3)
void ssim_main(const float* __restrict__ simg, const float* __restrict__ timg,
               float* __restrict__ accum) {
    __shared__ float hb[5][ITY][HBS];
    __shared__ float red[4];

    const int tid = threadIdx.x;

    // XCD-aware remap (XCD = linear_id % 8): each XCD owns 6 contiguous
    // slices; row-major 16x8 tiles within a slice. Perf-only.
    const int lin = blockIdx.x;
    const int t   = ((lin & 7) * (NBLK / 8)) + (lin >> 3);
    const int z   = t >> 7;           // slice (batch*channel), 128 tiles each
    const int rem = t & 127;
    const int ty  = rem >> 4;
    const int tx  = rem & 15;

    const float* sp = simg + (size_t)z * (W * H);
    const float* tp = timg + (size_t)z * (W * H);
    const int x0 = tx * TX;
    const int y0 = ty * TY - HALO;

    // ---- Horizontal pass: 74 rows x 8 quads = 592 items over 256 threads ----
    for (int it = tid; it < ITY * 8; it += 256) {
        const int yy = it >> 3;
        const int q  = it & 7;
        const int ox = q * 4;
        const int gy = y0 + yy;
        float hs[4]  = {0, 0, 0, 0};
        float ht[4]  = {0, 0, 0, 0};
        float hss[4] = {0, 0, 0, 0};
        float htt[4] = {0, 0, 0, 0};
        float hst[4] = {0, 0, 0, 0};
        if ((unsigned)gy < (unsigned)H) {
            const float* rs = sp + (size_t)gy * W;
            const float* rt = tp + (size_t)gy * W;
            const int xb = x0 + ox - 8;      // window elem u -> col xb+u; u=3..16 live
            float cs[20], ct[20];
            if (xb >= 0 && xb <= W - 20) {   // interior: 5+5 aligned float4
                #pragma unroll
                for (int i = 0; i < 5; ++i) {
                    const float4 a = *(const float4*)(rs + xb + 4 * i);
                    const float4 b = *(const float4*)(rt + xb + 4 * i);
                    cs[4*i+0] = a.x; cs[4*i+1] = a.y; cs[4*i+2] = a.z; cs[4*i+3] = a.w;
                    ct[4*i+0] = b.x; ct[4*i+1] = b.y; ct[4*i+2] = b.z; ct[4*i+3] = b.w;
                }
            } else {                          // edge: guard only 14 live elems
                #pragma unroll
                for (int u = 3; u <= 16; ++u) {
                    const int xx = xb + u;
                    const bool ok = (unsigned)xx < (unsigned)W;
                    cs[u] = ok ? rs[xx] : 0.f;
                    ct[u] = ok ? rt[xx] : 0.f;
                }
            }
            // out col (ox+m), tap k uses element u = m + k + 3
            #pragma unroll
            for (int u = 3; u <= 16; ++u) {
                const float sv = cs[u], tv = ct[u];
                const float ssv = sv * sv;
                const float ttv = tv * tv;
                const float stv = sv * tv;
                #pragma unroll
                for (int m = 0; m < 4; ++m) {
                    const int k = u - 3 - m;
                    if (k >= 0 && k < KS) {
                        const float gk = GW[k];
                        hs[m]  = fmaf(gk, sv,  hs[m]);
                        ht[m]  = fmaf(gk, tv,  ht[m]);
                        hss[m] = fmaf(gk, ssv, hss[m]);
                        htt[m] = fmaf(gk, ttv, htt[m]);
                        hst[m] = fmaf(gk, stv, hst[m]);
                    }
                }
            }
        }
        *(float4*)&hb[0][yy][ox] = make_float4(hs[0],  hs[1],  hs[2],  hs[3]);
        *(float4*)&hb[1][yy][ox] = make_float4(ht[0],  ht[1],  ht[2],  ht[3]);
        *(float4*)&hb[2][yy][ox] = make_float4(hss[0], hss[1], hss[2], hss[3]);
        *(float4*)&hb[3][yy][ox] = make_float4(htt[0], htt[1], htt[2], htt[3]);
        *(float4*)&hb[4][yy][ox] = make_float4(hst[0], hst[1], hst[2], hst[3]);
    }
    __syncthreads();

    // ---- Vertical pass: lane = x (conflict-free), 8 stacked y-outputs ----
    // 18 rows x 5 ch reads feed 440 FMAs (11.25 LDS reads / output px).
    const int x  = tid & 31;
    const int yb = (tid >> 5) * 8;
    float aux[8]  = {0, 0, 0, 0, 0, 0, 0, 0};
    float auy[8]  = {0, 0, 0, 0, 0, 0, 0, 0};
    float auxx[8] = {0, 0, 0, 0, 0, 0, 0, 0};
    float auyy[8] = {0, 0, 0, 0, 0, 0, 0, 0};
    float auxy[8] = {0, 0, 0, 0, 0, 0, 0, 0};
    #pragma unroll
    for (int k = 0; k < 18; ++k) {
        const float vx  = hb[0][yb + k][x];
        const float vy  = hb[1][yb + k][x];
        const float vxx = hb[2][yb + k][x];
        const float vyy = hb[3][yb + k][x];
        const float vxy = hb[4][yb + k][x];
        #pragma unroll
        for (int o = 0; o < 8; ++o) {
            const int j = k - o;
            if (j >= 0 && j < KS) {
                const float gj = GW[j];
                aux[o]  = fmaf(gj, vx,  aux[o]);
                auy[o]  = fmaf(gj, vy,  auy[o]);
                auxx[o] = fmaf(gj, vxx, auxx[o]);
                auyy[o] = fmaf(gj, vyy, auyy[o]);
                auxy[o] = fmaf(gj, vxy, auxy[o]);
            }
        }
    }
    float sum = 0.f;
    #pragma unroll
    for (int o = 0; o < 8; ++o)
        sum += ssim_px(aux[o], auy[o], auxx[o], auyy[o], auxy[o]);

    // ---- Block reduction, one atomic per block into a per-slice line ----
    #pragma unroll
    for (int off = 32; off > 0; off >>= 1)
        sum += __shfl_down(sum, off, 64);
    if ((tid & 63) == 0) red[tid >> 6] = sum;
    __syncthreads();
    if (tid == 0) {
        atomicAdd(&accum[z * 16], red[0] + red[1] + red[2] + red[3]);
    }
}

__global__ void ssim_final(const float* __restrict__ accum, float* __restrict__ out) {
    float s = 0.f;
    #pragma unroll
    for (int i = 0; i < NSLICES; ++i) s += accum[i * 16];
    out[0] = 1.f - s * (1.f / NTOTAL);
}

extern "C" void kernel_launch(void* const* d_in, const int* in_sizes, int n_in,
                              void* d_out, int out_size, void* d_ws, size_t ws_size,
                              hipStream_t stream) {
    const float* s = (const float*)d_in[0];
    const float* t = (const float*)d_in[1];
    float* out   = (float*)d_out;
    float* accum = (float*)d_ws;

    hipMemsetAsync(accum, 0, NSLICES * 16 * sizeof(float), stream);
    ssim_main<<<dim3(NBLK), 256, 0, stream>>>(s, t, accum);
    ssim_final<<<1, 1, 0, stream>>>(accum, out);
}

// Round 5
// 164.799 us; speedup vs baseline: 1.7105x; 1.0157x over previous
//
#include <hip/hip_runtime.h>

#define W 512
#define H 512
#define NSLICES 48          // 16 batch * 3 channels
#define TX 32
#define TY 64
#define HALO 5
#define KS 11
#define ITY (TY + 2*HALO)   // 74 hconv rows
#define HBS 32              // hb row stride
#define NITEMS (ITY * 4)    // 296 8-wide hconv items
#define NBLK 6144           // 16 x-tiles * 8 y-tiles * 48 slices
#define C1_SSIM 0.0001f
#define C2_SSIM 0.0009f
#define NTOTAL 12582912.0f  // 16*3*512*512

// Normalized separable Gaussian (ksize=11, sigma=1.5), f32; matches the
// reference's normalized row-sums to ~1e-7 (threshold 1.98e-2).
__device__ __constant__ const float GW[KS] = {
    1.02838e-3f, 7.59876e-3f, 3.600076e-2f, 1.0936069e-1f, 2.1300554e-1f,
    2.6601172e-1f,
    2.1300554e-1f, 1.0936069e-1f, 3.600076e-2f, 7.59876e-3f, 1.02838e-3f
};

__device__ inline float ssim_px(float ux, float uy, float uxx, float uyy, float uxy) {
    const float uxuy = ux * uy;
    const float a = 2.f * uxuy + C1_SSIM;
    const float b = 2.f * (uxy - uxuy) + C2_SSIM;
    const float c = ux * ux + uy * uy + C1_SSIM;
    const float d = (uxx - ux * ux) + (uyy - uy * uy) + C2_SSIM;
    return (a * b) * __builtin_amdgcn_rcpf(c * d);
}

// LDS: 5*74*32*4 = 47360 B -> 3 blocks/CU (12 waves).
__global__ __launch_bounds__(256, 3)
void ssim_main(const float* __restrict__ simg, const float* __restrict__ timg,
               float* __restrict__ accum) {
    __shared__ float hb[5][ITY][HBS];
    __shared__ float red[4];

    const int tid = threadIdx.x;

    // XCD-aware remap (XCD = linear_id % 8): each XCD owns 6 contiguous
    // slices; row-major 16x8 tiles within a slice. Perf-only.
    const int lin = blockIdx.x;
    const int t   = ((lin & 7) * (NBLK / 8)) + (lin >> 3);
    const int z   = t >> 7;           // slice (batch*channel), 128 tiles each
    const int rem = t & 127;
    const int ty  = rem >> 4;
    const int tx  = rem & 15;

    const float* sp = simg + (size_t)z * (W * H);
    const float* tp = timg + (size_t)z * (W * H);
    const int x0 = tx * TX;
    const int y0 = ty * TY - HALO;
    const bool x_interior = (tx > 0) && (tx < 15);  // block-uniform

    // ---- Horizontal pass: 74 rows x 4 8-wide items = 296 items ----
    // Per item: 12 float4 loads, 54 products, 440 FMAs, 10 b128 LDS stores.
    for (int it = tid; it < NITEMS; it += 256) {
        const int yy = it >> 2;
        const int q  = it & 3;
        const int ox = q * 8;
        const int gy = y0 + yy;
        float hs[8]  = {0,0,0,0,0,0,0,0};
        float ht[8]  = {0,0,0,0,0,0,0,0};
        float hss[8] = {0,0,0,0,0,0,0,0};
        float htt[8] = {0,0,0,0,0,0,0,0};
        float hst[8] = {0,0,0,0,0,0,0,0};
        if ((unsigned)gy < (unsigned)H) {
            const float* rs = sp + (size_t)gy * W;
            const float* rt = tp + (size_t)gy * W;
            const int xb = x0 + ox - 8;     // window elem u -> col xb+u; u=3..20 live
            float cs[24], ct[24];
            if (x_interior) {               // guard-free: 6+6 aligned float4
                #pragma unroll
                for (int i = 0; i < 6; ++i) {
                    const float4 a = *(const float4*)(rs + xb + 4 * i);
                    const float4 b = *(const float4*)(rt + xb + 4 * i);
                    cs[4*i+0] = a.x; cs[4*i+1] = a.y; cs[4*i+2] = a.z; cs[4*i+3] = a.w;
                    ct[4*i+0] = b.x; ct[4*i+1] = b.y; ct[4*i+2] = b.z; ct[4*i+3] = b.w;
                }
            } else {                        // x-edge tiles: guard 18 live elems
                #pragma unroll
                for (int u = 3; u <= 20; ++u) {
                    const int xx = xb + u;
                    const bool ok = (unsigned)xx < (unsigned)W;
                    cs[u] = ok ? rs[xx] : 0.f;
                    ct[u] = ok ? rt[xx] : 0.f;
                }
            }
            // out col (ox+m), tap k uses element u = m + k + 3
            #pragma unroll
            for (int u = 3; u <= 20; ++u) {
                const float sv = cs[u], tv = ct[u];
                const float ssv = sv * sv;
                const float ttv = tv * tv;
                const float stv = sv * tv;
                #pragma unroll
                for (int m = 0; m < 8; ++m) {
                    const int k = u - 3 - m;
                    if (k >= 0 && k < KS) {
                        const float gk = GW[k];
                        hs[m]  = fmaf(gk, sv,  hs[m]);
                        ht[m]  = fmaf(gk, tv,  ht[m]);
                        hss[m] = fmaf(gk, ssv, hss[m]);
                        htt[m] = fmaf(gk, ttv, htt[m]);
                        hst[m] = fmaf(gk, stv, hst[m]);
                    }
                }
            }
        }
        *(float4*)&hb[0][yy][ox]     = make_float4(hs[0],  hs[1],  hs[2],  hs[3]);
        *(float4*)&hb[0][yy][ox + 4] = make_float4(hs[4],  hs[5],  hs[6],  hs[7]);
        *(float4*)&hb[1][yy][ox]     = make_float4(ht[0],  ht[1],  ht[2],  ht[3]);
        *(float4*)&hb[1][yy][ox + 4] = make_float4(ht[4],  ht[5],  ht[6],  ht[7]);
        *(float4*)&hb[2][yy][ox]     = make_float4(hss[0], hss[1], hss[2], hss[3]);
        *(float4*)&hb[2][yy][ox + 4] = make_float4(hss[4], hss[5], hss[6], hss[7]);
        *(float4*)&hb[3][yy][ox]     = make_float4(htt[0], htt[1], htt[2], htt[3]);
        *(float4*)&hb[3][yy][ox + 4] = make_float4(htt[4], htt[5], htt[6], htt[7]);
        *(float4*)&hb[4][yy][ox]     = make_float4(hst[0], hst[1], hst[2], hst[3]);
        *(float4*)&hb[4][yy][ox + 4] = make_float4(hst[4], hst[5], hst[6], hst[7]);
    }
    __syncthreads();

    // ---- Vertical pass: lane = x (proven conflict-free), 8 y-outputs ----
    const int x  = tid & 31;
    const int yb = (tid >> 5) * 8;
    float aux[8]  = {0,0,0,0,0,0,0,0};
    float auy[8]  = {0,0,0,0,0,0,0,0};
    float auxx[8] = {0,0,0,0,0,0,0,0};
    float auyy[8] = {0,0,0,0,0,0,0,0};
    float auxy[8] = {0,0,0,0,0,0,0,0};
    #pragma unroll
    for (int k = 0; k < 18; ++k) {
        const float vx  = hb[0][yb + k][x];
        const float vy  = hb[1][yb + k][x];
        const float vxx = hb[2][yb + k][x];
        const float vyy = hb[3][yb + k][x];
        const float vxy = hb[4][yb + k][x];
        #pragma unroll
        for (int o = 0; o < 8; ++o) {
            const int j = k - o;
            if (j >= 0 && j < KS) {
                const float gj = GW[j];
                aux[o]  = fmaf(gj, vx,  aux[o]);
                auy[o]  = fmaf(gj, vy,  auy[o]);
                auxx[o] = fmaf(gj, vxx, auxx[o]);
                auyy[o] = fmaf(gj, vyy, auyy[o]);
                auxy[o] = fmaf(gj, vxy, auxy[o]);
            }
        }
    }
    float sum = 0.f;
    #pragma unroll
    for (int o = 0; o < 8; ++o)
        sum += ssim_px(aux[o], auy[o], auxx[o], auyy[o], auxy[o]);

    // ---- Block reduction, one atomic per block into a per-slice line ----
    #pragma unroll
    for (int off = 32; off > 0; off >>= 1)
        sum += __shfl_down(sum, off, 64);
    if ((tid & 63) == 0) red[tid >> 6] = sum;
    __syncthreads();
    if (tid == 0) {
        atomicAdd(&accum[z * 16], red[0] + red[1] + red[2] + red[3]);
    }
}

__global__ void ssim_final(const float* __restrict__ accum, float* __restrict__ out) {
    float s = 0.f;
    #pragma unroll
    for (int i = 0; i < NSLICES; ++i) s += accum[i * 16];
    out[0] = 1.f - s * (1.f / NTOTAL);
}

extern "C" void kernel_launch(void* const* d_in, const int* in_sizes, int n_in,
                              void* d_out, int out_size, void* d_ws, size_t ws_size,
                              hipStream_t stream) {
    const float* s = (const float*)d_in[0];
    const float* t = (const float*)d_in[1];
    float* out   = (float*)d_out;
    float* accum = (float*)d_ws;

    hipMemsetAsync(accum, 0, NSLICES * 16 * sizeof(float), stream);
    ssim_main<<<dim3(NBLK), 256, 0, stream>>>(s, t, accum);
    ssim_final<<<1, 1, 0, stream>>>(accum, out);
}